// Round 9
// baseline (582.959 us; speedup 1.0000x reference)
//
#include <hip/hip_runtime.h>

// GNNPolicy forward: 2-layer GCN (edge-weighted, symmetric norm, self-loops)
// + per-node actor head + per-graph mean-pool critic head.
// All f32. N=100K nodes, E=1.6M edges, H=64 hidden, G=64 graphs.
// CSR build via two-phase coarse-bucket binning: dense appends (pass A) +
// per-bucket LDS bin/scan (pass B). No full-line-per-edge random writes.

#define TB 256
#define BSH 5
#define BW 32            // bucket width = 1<<BSH cols per coarse bucket

// ---- pass A: append packed (local_col, eid) records to coarse buckets ----
// record = (col & 31) << 27 | eid   (eid < 2^27; E=1.6M fits)
__global__ void passA_k(const int* __restrict__ col, int* __restrict__ cursorB,
                        unsigned* __restrict__ recA, int E, int CAPB) {
    int e = blockIdx.x * blockDim.x + threadIdx.x;
    if (e >= E) return;
    int c = col[e];
    int b = c >> BSH;
    int pos = atomicAdd(&cursorB[b], 1);
    if (pos < CAPB)      // overflow ~impossible (CAPB ~ 1.6x mean); guard anyway
        recA[(size_t)b * CAPB + pos] = ((unsigned)(c & (BW - 1)) << 27) | (unsigned)e;
}

// ---- pass B: one block per bucket; bin by exact col, emit eids + ptr/cnt ----
__global__ __launch_bounds__(256) void passB_k(const int* __restrict__ cursorB,
                                               const unsigned* __restrict__ recA,
                                               int* __restrict__ eid_out,
                                               int* __restrict__ ptr,
                                               int* __restrict__ cnt,
                                               int N, int CAPB) {
    __shared__ int cntL[BW], curL[BW], exclL[BW];
    int b = blockIdx.x;
    int t = threadIdx.x;
    int nrec = min(cursorB[b], CAPB);
    if (t < BW) { cntL[t] = 0; curL[t] = 0; }
    __syncthreads();
    const unsigned* rb = recA + (size_t)b * CAPB;
    for (int i = t; i < nrec; i += 256) atomicAdd(&cntL[rb[i] >> 27], 1);
    __syncthreads();
    if (t == 0) {
        int s = 0;
        for (int j = 0; j < BW; ++j) { exclL[j] = s; s += cntL[j]; }
    }
    __syncthreads();
    for (int i = t; i < nrec; i += 256) {       // recA bucket is L2-hot (re-read)
        unsigned r = rb[i];
        int lc = r >> 27;
        int pos = atomicAdd(&curL[lc], 1);
        eid_out[(size_t)b * CAPB + exclL[lc] + pos] = (int)(r & 0x07FFFFFFu);
    }
    int c0 = b << BSH;
    if (t < BW && c0 + t < N) {
        ptr[c0 + t] = b * CAPB + exclL[t];
        cnt[c0 + t] = cntL[t];
    }
}

// deg[n] = sum |ea| over in-edges -> dis = rsqrt(deg+1). Wave per node.
__global__ __launch_bounds__(256) void deg_dis_k(const int* __restrict__ ptr,
                                                 const int* __restrict__ cnt,
                                                 const int* __restrict__ eid,
                                                 const float* __restrict__ ea,
                                                 float* __restrict__ dis, int N) {
    int n = blockIdx.x * 4 + (threadIdx.x >> 6);
    if (n >= N) return;
    int lane = threadIdx.x & 63;
    int base = ptr[n], num = cnt[n];
    float a = 0.f;
    for (int k = lane; k < num; k += 64)
        a += fabsf(ea[eid[base + k]]);           // coalesced eid, random 4B ea
    for (int off = 32; off; off >>= 1) a += __shfl_down(a, off);
    if (lane == 0) dis[n] = rsqrtf(a + 1.0f);
}

// Y[N,64] = X[N,K] @ W[K,64].  Block: 256 thr = 16 rows x 64 cols, 4 rows/thread.
template <int K>
__global__ __launch_bounds__(256) void gemm_k(const float* __restrict__ X,
                                              const float* __restrict__ W,
                                              float* __restrict__ Y, int N) {
    __shared__ float xs[16 * K];
    const int tid = threadIdx.x;
    const int row0 = blockIdx.x * 16;
    const float4* X4 = reinterpret_cast<const float4*>(X + (size_t)row0 * K);
    float4* xs4 = reinterpret_cast<float4*>(xs);
    for (int idx = tid; idx < 16 * K / 4; idx += 256) {
        int r = row0 + (idx * 4) / K;
        xs4[idx] = (r < N) ? X4[idx] : float4{0.f, 0.f, 0.f, 0.f};
    }
    __syncthreads();
    const int c  = tid & 63;
    const int rg = tid >> 6;
    const float4* xp0 = reinterpret_cast<const float4*>(xs + (rg * 4 + 0) * K);
    const float4* xp1 = reinterpret_cast<const float4*>(xs + (rg * 4 + 1) * K);
    const float4* xp2 = reinterpret_cast<const float4*>(xs + (rg * 4 + 2) * K);
    const float4* xp3 = reinterpret_cast<const float4*>(xs + (rg * 4 + 3) * K);
    float a0 = 0.f, a1 = 0.f, a2 = 0.f, a3 = 0.f;
#pragma unroll 2
    for (int k4 = 0; k4 < K / 4; ++k4) {
        float4 x0 = xp0[k4], x1 = xp1[k4], x2 = xp2[k4], x3 = xp3[k4];
        const float* wp = W + k4 * 4 * 64 + c;
        float w0 = wp[0], w1 = wp[64], w2 = wp[128], w3 = wp[192];
        a0 = fmaf(x0.x, w0, a0); a0 = fmaf(x0.y, w1, a0);
        a0 = fmaf(x0.z, w2, a0); a0 = fmaf(x0.w, w3, a0);
        a1 = fmaf(x1.x, w0, a1); a1 = fmaf(x1.y, w1, a1);
        a1 = fmaf(x1.z, w2, a1); a1 = fmaf(x1.w, w3, a1);
        a2 = fmaf(x2.x, w0, a2); a2 = fmaf(x2.y, w1, a2);
        a2 = fmaf(x2.z, w2, a2); a2 = fmaf(x2.w, w3, a2);
        a3 = fmaf(x3.x, w0, a3); a3 = fmaf(x3.y, w1, a3);
        a3 = fmaf(x3.z, w2, a3); a3 = fmaf(x3.w, w3, a3);
    }
    int r = row0 + rg * 4;
    if (r < N)     Y[(size_t)r * 64 + c]       = a0;
    if (r + 1 < N) Y[(size_t)(r + 1) * 64 + c] = a1;
    if (r + 2 < N) Y[(size_t)(r + 2) * 64 + c] = a2;
    if (r + 3 < N) Y[(size_t)(r + 3) * 64 + c] = a3;
}

// CSR gather aggregation fused with self-loop + bias + ReLU.
// Wave per node, lane = feature. Chunked prologue: lanes pre-gather edge meta
// (64 at a time), shfl-broadcast per edge into the coalesced xw gather.
__global__ __launch_bounds__(256) void agg_fin_k(const int* __restrict__ ptr,
                                                 const int* __restrict__ cnt,
                                                 const int* __restrict__ eid,
                                                 const int* __restrict__ row,
                                                 const float* __restrict__ ea,
                                                 const float* __restrict__ dis,
                                                 const float* __restrict__ xw,
                                                 const float* __restrict__ bias,
                                                 float* __restrict__ h, int N) {
    int n = blockIdx.x * 4 + (threadIdx.x >> 6);
    if (n >= N) return;
    int lane = threadIdx.x & 63;
    int base = ptr[n], num = cnt[n];
    float acc = 0.f;
    for (int k0 = 0; k0 < num; k0 += 64) {
        int rem = min(num - k0, 64);
        float w = 0.f; int r = 0;
        if (lane < rem) {
            int e = eid[base + k0 + lane];       // coalesced
            r = row[e];                          // parallel random 4B gathers
            w = fabsf(ea[e]) * dis[r];
        }
        for (int k = 0; k < rem; ++k) {
            int   rk = __shfl(r, k);
            float wk = __shfl(w, k);
            acc = fmaf(wk, xw[(size_t)rk * 64 + lane], acc);  // coalesced 256B
        }
    }
    float d = dis[n];
    float sv = fmaf(d, xw[(size_t)n * 64 + lane], acc);       // acc + d*xw_self
    h[(size_t)n * 64 + lane] = fmaxf(fmaf(d, sv, bias[lane]), 0.0f);
}

// Segmented heads: wave per contiguous node chunk; register pool accumulation,
// one coalesced atomic row per graph transition (batch is sorted).
__global__ __launch_bounds__(256) void heads_k(const float* __restrict__ h,
                                               const float* __restrict__ aw,
                                               const float* __restrict__ ab,
                                               const int* __restrict__ batch,
                                               float* __restrict__ logits,
                                               float* __restrict__ sums,
                                               float* __restrict__ counts,
                                               int N, int C) {
    int wave = blockIdx.x * 4 + (threadIdx.x >> 6);
    int lane = threadIdx.x & 63;
    int start = wave * C;
    if (start >= N) return;
    int end = min(start + C, N);
    float aww = aw[lane];
    float abv = ab[0];
    int cur = batch[start];
    float acc = 0.f;
    int cntv = 0;
    for (int i = start; i < end; ++i) {
        float hv = h[(size_t)i * 64 + lane];
        float p = hv * aww;
        for (int off = 32; off; off >>= 1) p += __shfl_down(p, off);
        if (lane == 0) logits[i] = p + abv;
        int g = batch[i];                      // wave-uniform
        if (g != cur) {
            atomicAdd(&sums[cur * 64 + lane], acc);
            if (lane == 0) atomicAdd(&counts[cur], (float)cntv);
            acc = 0.f; cntv = 0; cur = g;
        }
        acc += hv; ++cntv;
    }
    atomicAdd(&sums[cur * 64 + lane], acc);
    if (lane == 0) atomicAdd(&counts[cur], (float)cntv);
}

__global__ void value_k(const float* __restrict__ sums, const float* __restrict__ counts,
                        const float* __restrict__ cw, const float* __restrict__ cb,
                        float* __restrict__ val) {
    int g = blockIdx.x;
    int lane = threadIdx.x;  // block 64
    float cntv = fmaxf(counts[g], 1.0f);
    float p = (sums[g * 64 + lane] / cntv) * cw[lane];
    for (int off = 32; off; off >>= 1) p += __shfl_down(p, off);
    if (lane == 0) val[g] = p + cb[0];
}

extern "C" void kernel_launch(void* const* d_in, const int* in_sizes, int n_in,
                              void* d_out, int out_size, void* d_ws, size_t ws_size,
                              hipStream_t stream) {
    const float* x     = (const float*)d_in[0];
    const int*   ei    = (const int*)d_in[1];
    const float* ea    = (const float*)d_in[2];
    const int*   batch = (const int*)d_in[3];
    const float* W1    = (const float*)d_in[4];
    const float* b1    = (const float*)d_in[5];
    const float* W2    = (const float*)d_in[6];
    const float* b2    = (const float*)d_in[7];
    const float* aw    = (const float*)d_in[8];
    const float* ab    = (const float*)d_in[9];
    const float* cw    = (const float*)d_in[10];
    const float* cb    = (const float*)d_in[11];

    const int N = in_sizes[3];
    const int E = in_sizes[2];
    const int H = 64, G = 64;
    const int* row = ei;
    const int* col = ei + E;

    const int NBUK = (N + BW - 1) >> BSH;            // coarse buckets
    const int CAPB = (E / NBUK) * 3 / 2 + 64;        // ~1.6x mean (+slack)

    // workspace layout (~72 MB)
    float*    dis     = (float*)d_ws;                        // N
    int*      cursorB = (int*)(dis + N);                     // NBUK
    unsigned* recA    = (unsigned*)(cursorB + NBUK);         // NBUK*CAPB
    int*      eid     = (int*)(recA + (size_t)NBUK * CAPB);  // NBUK*CAPB
    int*      ptr     = eid + (size_t)NBUK * CAPB;           // N
    int*      cnt     = ptr + N;                             // N
    float*    bufA    = (float*)(cnt + N);                   // N*H
    float*    bufB    = bufA + (size_t)N * H;                // N*H
    float*    sums    = bufB + (size_t)N * H;                // G*H
    float*    counts  = sums + G * H;                        // G

    float* logits = (float*)d_out;              // N
    float* value  = logits + N;                 // G

    // ---- CSR build: dense-append binning (shared by both layers) ----
    hipMemsetAsync(cursorB, 0, (size_t)NBUK * 4, stream);
    passA_k<<<(E + TB - 1) / TB, TB, 0, stream>>>(col, cursorB, recA, E, CAPB);
    passB_k<<<NBUK, 256, 0, stream>>>(cursorB, recA, eid, ptr, cnt, N, CAPB);
    deg_dis_k<<<(N + 3) / 4, 256, 0, stream>>>(ptr, cnt, eid, ea, dis, N);

    // ---- layer 1 ----
    gemm_k<128><<<(N + 15) / 16, 256, 0, stream>>>(x, W1, bufA, N);
    agg_fin_k<<<(N + 3) / 4, 256, 0, stream>>>(ptr, cnt, eid, row, ea, dis, bufA, b1, bufB, N);

    // ---- layer 2 ----
    gemm_k<64><<<(N + 15) / 16, 256, 0, stream>>>(bufB, W2, bufA, N);
    agg_fin_k<<<(N + 3) / 4, 256, 0, stream>>>(ptr, cnt, eid, row, ea, dis, bufA, b2, bufB, N);

    // ---- heads (segmented; batch sorted) ----
    hipMemsetAsync(sums, 0, (size_t)(G * H + G) * 4, stream);
    const int WAVES = 4096;
    const int C = (N + WAVES - 1) / WAVES;
    heads_k<<<WAVES / 4, 256, 0, stream>>>(bufB, aw, ab, batch, logits, sums, counts, N, C);
    value_k<<<G, 64, 0, stream>>>(sums, counts, cw, cb, value);
}

// Round 10
// 370.188 us; speedup vs baseline: 1.5748x; 1.5748x over previous
//
#include <hip/hip_runtime.h>

// GNNPolicy forward: 2-layer GCN + actor head + mean-pool critic head. f32.
// N=100K, E=1.6M, H=64, G=64.
// CSR build: 2-level counting sort with block-private region reservations
// (dense writes, no cross-CU line ping-pong). Final CSR rec = (row, |ea|).
// Aggregation: wave-per-node gather, 4-wide unrolled for memory-level par.

#define TB 256
#define BSH2 9
#define BW2 512          // nodes per coarse bucket
#define CHUNK 4096       // edges per passA block
#define NB1MAX 256

// ---- pass A: per-block LDS histogram + region reservation + dense append ----
// recA = (colLocal<<21) | eid   (eid < 2^21, colLocal < 512)
__global__ __launch_bounds__(256) void passA_k(const int* __restrict__ col,
                                               int* __restrict__ gCur,
                                               unsigned* __restrict__ recA,
                                               int E, int CAPB, int NB1) {
    __shared__ int hist[NB1MAX], base[NB1MAX], cur[NB1MAX];
    int t = threadIdx.x;
    int e0 = blockIdx.x * CHUNK;
    if (t < NB1MAX) { hist[t] = 0; cur[t] = 0; }
    __syncthreads();
    for (int i = t; i < CHUNK; i += 256) {
        int e = e0 + i;
        if (e < E) atomicAdd(&hist[col[e] >> BSH2], 1);
    }
    __syncthreads();
    if (t < NB1) base[t] = atomicAdd(&gCur[t], hist[t]);   // one reservation per bucket
    __syncthreads();
    for (int i = t; i < CHUNK; i += 256) {
        int e = e0 + i;
        if (e >= E) continue;
        int c = col[e];
        int b = c >> BSH2;
        int pos = base[b] + atomicAdd(&cur[b], 1);
        if (pos < CAPB)   // statistically impossible overflow; guard anyway
            recA[(size_t)b * CAPB + pos] =
                ((unsigned)(c & (BW2 - 1)) << 21) | (unsigned)e;
    }
}

// ---- pass B: per-bucket exact binning -> final CSR (row, |ea|) + ptr/cnt ----
__global__ __launch_bounds__(256) void passB_k(const int* __restrict__ gCur,
                                               const unsigned* __restrict__ recA,
                                               const int* __restrict__ row,
                                               const float* __restrict__ ea,
                                               uint2* __restrict__ rec,
                                               int* __restrict__ ptr,
                                               int* __restrict__ cnt,
                                               int N, int CAPB) {
    __shared__ int hist[BW2], excl[BW2], cur[BW2];
    __shared__ int part[256];
    int b = blockIdx.x, t = threadIdx.x;
    int nrec = min(gCur[b], CAPB);
    for (int i = t; i < BW2; i += 256) { hist[i] = 0; cur[i] = 0; }
    __syncthreads();
    const unsigned* ra = recA + (size_t)b * CAPB;
    for (int i = t; i < nrec; i += 256) atomicAdd(&hist[ra[i] >> 21], 1);
    __syncthreads();
    // block exclusive scan over 512 counters (2 per thread)
    int s0 = hist[t * 2], s = s0 + hist[t * 2 + 1];
    part[t] = s;
    __syncthreads();
    for (int d = 1; d < 256; d <<= 1) {
        int v = (t >= d) ? part[t - d] : 0;
        __syncthreads();
        part[t] += v;
        __syncthreads();
    }
    int poff = t ? part[t - 1] : 0;
    excl[t * 2] = poff;
    excl[t * 2 + 1] = poff + s0;
    __syncthreads();
    // scatter records to exact CSR slots (writes land in a ~84KB L2 window)
    for (int i = t; i < nrec; i += 256) {
        unsigned r = ra[i];
        int lc = r >> 21;
        int e  = (int)(r & 0x1FFFFFu);
        int pos = atomicAdd(&cur[lc], 1);
        rec[(size_t)b * CAPB + excl[lc] + pos] =
            make_uint2((unsigned)row[e], __float_as_uint(fabsf(ea[e])));
    }
    int c0 = b << BSH2;
    for (int i = t; i < BW2; i += 256) {
        int node = c0 + i;
        if (node < N) { ptr[node] = b * CAPB + excl[i]; cnt[node] = hist[i]; }
    }
}

// deg[n] = sum |ea| over in-edges (coalesced CSR reads) -> dis = rsqrt(deg+1)
__global__ __launch_bounds__(256) void deg_dis_k(const int* __restrict__ ptr,
                                                 const int* __restrict__ cnt,
                                                 const uint2* __restrict__ rec,
                                                 float* __restrict__ dis, int N) {
    int n = blockIdx.x * 4 + (threadIdx.x >> 6);
    if (n >= N) return;
    int lane = threadIdx.x & 63;
    int base = ptr[n], num = cnt[n];
    float a = 0.f;
    for (int k = lane; k < num; k += 64)
        a += __uint_as_float(rec[(size_t)base + k].y);
    for (int off = 32; off; off >>= 1) a += __shfl_down(a, off);
    if (lane == 0) dis[n] = rsqrtf(a + 1.0f);
}

// Y[N,64] = X[N,K] @ W[K,64].  Block: 256 thr = 16 rows x 64 cols, 4 rows/thread.
template <int K>
__global__ __launch_bounds__(256) void gemm_k(const float* __restrict__ X,
                                              const float* __restrict__ W,
                                              float* __restrict__ Y, int N) {
    __shared__ float xs[16 * K];
    const int tid = threadIdx.x;
    const int row0 = blockIdx.x * 16;
    const float4* X4 = reinterpret_cast<const float4*>(X + (size_t)row0 * K);
    float4* xs4 = reinterpret_cast<float4*>(xs);
    for (int idx = tid; idx < 16 * K / 4; idx += 256) {
        int r = row0 + (idx * 4) / K;
        xs4[idx] = (r < N) ? X4[idx] : float4{0.f, 0.f, 0.f, 0.f};
    }
    __syncthreads();
    const int c  = tid & 63;
    const int rg = tid >> 6;
    const float4* xp0 = reinterpret_cast<const float4*>(xs + (rg * 4 + 0) * K);
    const float4* xp1 = reinterpret_cast<const float4*>(xs + (rg * 4 + 1) * K);
    const float4* xp2 = reinterpret_cast<const float4*>(xs + (rg * 4 + 2) * K);
    const float4* xp3 = reinterpret_cast<const float4*>(xs + (rg * 4 + 3) * K);
    float a0 = 0.f, a1 = 0.f, a2 = 0.f, a3 = 0.f;
#pragma unroll 2
    for (int k4 = 0; k4 < K / 4; ++k4) {
        float4 x0 = xp0[k4], x1 = xp1[k4], x2 = xp2[k4], x3 = xp3[k4];
        const float* wp = W + k4 * 4 * 64 + c;
        float w0 = wp[0], w1 = wp[64], w2 = wp[128], w3 = wp[192];
        a0 = fmaf(x0.x, w0, a0); a0 = fmaf(x0.y, w1, a0);
        a0 = fmaf(x0.z, w2, a0); a0 = fmaf(x0.w, w3, a0);
        a1 = fmaf(x1.x, w0, a1); a1 = fmaf(x1.y, w1, a1);
        a1 = fmaf(x1.z, w2, a1); a1 = fmaf(x1.w, w3, a1);
        a2 = fmaf(x2.x, w0, a2); a2 = fmaf(x2.y, w1, a2);
        a2 = fmaf(x2.z, w2, a2); a2 = fmaf(x2.w, w3, a2);
        a3 = fmaf(x3.x, w0, a3); a3 = fmaf(x3.y, w1, a3);
        a3 = fmaf(x3.z, w2, a3); a3 = fmaf(x3.w, w3, a3);
    }
    int r = row0 + rg * 4;
    if (r < N)     Y[(size_t)r * 64 + c]       = a0;
    if (r + 1 < N) Y[(size_t)(r + 1) * 64 + c] = a1;
    if (r + 2 < N) Y[(size_t)(r + 2) * 64 + c] = a2;
    if (r + 3 < N) Y[(size_t)(r + 3) * 64 + c] = a3;
}

// CSR gather aggregation fused with self-loop + bias + ReLU.
// Wave per node, lane = feature. 64-edge chunks: coalesced rec read + L2-hot
// dis gather, then 4-wide unrolled shfl-broadcast loop -> 4 xw gathers in
// flight per wave (memory-level parallelism; was the 148us latency limiter).
__global__ __launch_bounds__(256) void agg_fin_k(const int* __restrict__ ptr,
                                                 const int* __restrict__ cnt,
                                                 const uint2* __restrict__ rec,
                                                 const float* __restrict__ dis,
                                                 const float* __restrict__ xw,
                                                 const float* __restrict__ bias,
                                                 float* __restrict__ h, int N) {
    int n = blockIdx.x * 4 + (threadIdx.x >> 6);
    if (n >= N) return;
    int lane = threadIdx.x & 63;
    int base = ptr[n], num = cnt[n];
    float acc = 0.f;
    for (int k0 = 0; k0 < num; k0 += 64) {
        int rem = min(num - k0, 64);
        int r = 0; float w = 0.f;
        if (lane < rem) {
            uint2 rv = rec[(size_t)base + k0 + lane];   // coalesced 512B
            r = (int)rv.x;
            w = __uint_as_float(rv.y) * dis[r];         // 400KB table: L2-hot
        }
        int k = 0;
        for (; k + 3 < rem; k += 4) {
            int   r0 = __shfl(r, k),     r1 = __shfl(r, k + 1);
            int   r2 = __shfl(r, k + 2), r3 = __shfl(r, k + 3);
            float w0 = __shfl(w, k),     w1 = __shfl(w, k + 1);
            float w2 = __shfl(w, k + 2), w3 = __shfl(w, k + 3);
            float v0 = xw[(size_t)r0 * 64 + lane];
            float v1 = xw[(size_t)r1 * 64 + lane];
            float v2 = xw[(size_t)r2 * 64 + lane];
            float v3 = xw[(size_t)r3 * 64 + lane];
            acc = fmaf(w0, v0, acc); acc = fmaf(w1, v1, acc);
            acc = fmaf(w2, v2, acc); acc = fmaf(w3, v3, acc);
        }
        for (; k < rem; ++k) {
            int rk = __shfl(r, k); float wk = __shfl(w, k);
            acc = fmaf(wk, xw[(size_t)rk * 64 + lane], acc);
        }
    }
    float d = dis[n];
    float sv = fmaf(d, xw[(size_t)n * 64 + lane], acc);
    h[(size_t)n * 64 + lane] = fmaxf(fmaf(d, sv, bias[lane]), 0.0f);
}

// Segmented heads: wave per contiguous node chunk; register pool accumulation,
// one coalesced atomic row per graph transition (batch is sorted).
__global__ __launch_bounds__(256) void heads_k(const float* __restrict__ h,
                                               const float* __restrict__ aw,
                                               const float* __restrict__ ab,
                                               const int* __restrict__ batch,
                                               float* __restrict__ logits,
                                               float* __restrict__ sums,
                                               float* __restrict__ counts,
                                               int N, int C) {
    int wave = blockIdx.x * 4 + (threadIdx.x >> 6);
    int lane = threadIdx.x & 63;
    int start = wave * C;
    if (start >= N) return;
    int end = min(start + C, N);
    float aww = aw[lane];
    float abv = ab[0];
    int cur = batch[start];
    float acc = 0.f;
    int cntv = 0;
    for (int i = start; i < end; ++i) {
        float hv = h[(size_t)i * 64 + lane];
        float p = hv * aww;
        for (int off = 32; off; off >>= 1) p += __shfl_down(p, off);
        if (lane == 0) logits[i] = p + abv;
        int g = batch[i];                      // wave-uniform
        if (g != cur) {
            atomicAdd(&sums[cur * 64 + lane], acc);
            if (lane == 0) atomicAdd(&counts[cur], (float)cntv);
            acc = 0.f; cntv = 0; cur = g;
        }
        acc += hv; ++cntv;
    }
    atomicAdd(&sums[cur * 64 + lane], acc);
    if (lane == 0) atomicAdd(&counts[cur], (float)cntv);
}

__global__ void value_k(const float* __restrict__ sums, const float* __restrict__ counts,
                        const float* __restrict__ cw, const float* __restrict__ cb,
                        float* __restrict__ val) {
    int g = blockIdx.x;
    int lane = threadIdx.x;  // block 64
    float cntv = fmaxf(counts[g], 1.0f);
    float p = (sums[g * 64 + lane] / cntv) * cw[lane];
    for (int off = 32; off; off >>= 1) p += __shfl_down(p, off);
    if (lane == 0) val[g] = p + cb[0];
}

extern "C" void kernel_launch(void* const* d_in, const int* in_sizes, int n_in,
                              void* d_out, int out_size, void* d_ws, size_t ws_size,
                              hipStream_t stream) {
    const float* x     = (const float*)d_in[0];
    const int*   ei    = (const int*)d_in[1];
    const float* ea    = (const float*)d_in[2];
    const int*   batch = (const int*)d_in[3];
    const float* W1    = (const float*)d_in[4];
    const float* b1    = (const float*)d_in[5];
    const float* W2    = (const float*)d_in[6];
    const float* b2    = (const float*)d_in[7];
    const float* aw    = (const float*)d_in[8];
    const float* ab    = (const float*)d_in[9];
    const float* cw    = (const float*)d_in[10];
    const float* cb    = (const float*)d_in[11];

    const int N = in_sizes[3];
    const int E = in_sizes[2];
    const int H = 64, G = 64;
    const int* row = ei;
    const int* col = ei + E;

    const int NB1  = (N + BW2 - 1) >> BSH2;               // coarse buckets (<=256)
    const int CAPB = (((E / NB1) * 5 / 4 + 256) + 1) & ~1; // ~1.25x mean, even

    // workspace layout (~77 MB)
    float*    dis  = (float*)d_ws;                          // N
    int*      gCur = (int*)(dis + N);                       // NB1MAX
    unsigned* recA = (unsigned*)(gCur + NB1MAX);            // NB1*CAPB
    uint2*    rec  = (uint2*)(recA + (size_t)NB1 * CAPB);   // NB1*CAPB (8B)
    int*      ptr  = (int*)(rec + (size_t)NB1 * CAPB);      // N
    int*      cnt  = ptr + N;                               // N
    float*    bufA = (float*)(cnt + N);                     // N*H
    float*    bufB = bufA + (size_t)N * H;                  // N*H
    float*    sums = bufB + (size_t)N * H;                  // G*H
    float*    counts = sums + G * H;                        // G

    float* logits = (float*)d_out;              // N
    float* value  = logits + N;                 // G

    // ---- CSR build (shared by both layers) ----
    hipMemsetAsync(gCur, 0, (size_t)NB1MAX * 4, stream);
    passA_k<<<(E + CHUNK - 1) / CHUNK, 256, 0, stream>>>(col, gCur, recA, E, CAPB, NB1);
    passB_k<<<NB1, 256, 0, stream>>>(gCur, recA, row, ea, rec, ptr, cnt, N, CAPB);
    deg_dis_k<<<(N + 3) / 4, 256, 0, stream>>>(ptr, cnt, rec, dis, N);

    // ---- layer 1 ----
    gemm_k<128><<<(N + 15) / 16, 256, 0, stream>>>(x, W1, bufA, N);
    agg_fin_k<<<(N + 3) / 4, 256, 0, stream>>>(ptr, cnt, rec, dis, bufA, b1, bufB, N);

    // ---- layer 2 ----
    gemm_k<64><<<(N + 15) / 16, 256, 0, stream>>>(bufB, W2, bufA, N);
    agg_fin_k<<<(N + 3) / 4, 256, 0, stream>>>(ptr, cnt, rec, dis, bufA, b2, bufB, N);

    // ---- heads (segmented; batch sorted) ----
    hipMemsetAsync(sums, 0, (size_t)(G * H + G) * 4, stream);
    const int WAVES = 4096;
    const int C = (N + WAVES - 1) / WAVES;
    heads_k<<<WAVES / 4, 256, 0, stream>>>(bufB, aw, ab, batch, logits, sums, counts, N, C);
    value_k<<<G, 64, 0, stream>>>(sums, counts, cw, cb, value);
}

// Round 11
// 278.032 us; speedup vs baseline: 2.0967x; 1.3315x over previous
//
#include <hip/hip_runtime.h>
#include <hip/hip_fp16.h>

// GNNPolicy forward: 2-layer GCN + actor head + mean-pool critic head.
// N=100K, E=1.6M, H=64, G=64. CSR build: 2-level counting sort with
// block-private reservations; records carry (row,|ea|) so pass B needs no
// random gathers; deg/dis folded into pass B. xw stored fp16 to halve the
// dominant random-gather traffic in agg_fin (accumulation stays f32).

#define TB 256
#define BSH2 9
#define BW2 512          // nodes per coarse bucket
#define CHUNK 4096       // edges per passA block
#define NB1MAX 256       // max coarse buckets (N <= 131072, row fits 17 bits)

// ---- pass A: LDS histogram + region reservation + dense 8B-record append ----
// recA = ( (colLocal<<17) | row , |ea| )
__global__ __launch_bounds__(256) void passA_k(const int* __restrict__ col,
                                               const int* __restrict__ row,
                                               const float* __restrict__ ea,
                                               int* __restrict__ gCur,
                                               uint2* __restrict__ recA,
                                               int E, int CAPB, int NB1) {
    __shared__ int hist[NB1MAX], base[NB1MAX], cur[NB1MAX];
    int t = threadIdx.x;
    int e0 = blockIdx.x * CHUNK;
    if (t < NB1MAX) { hist[t] = 0; cur[t] = 0; }
    __syncthreads();
    for (int i = t; i < CHUNK; i += 256) {
        int e = e0 + i;
        if (e < E) atomicAdd(&hist[col[e] >> BSH2], 1);
    }
    __syncthreads();
    if (t < NB1) base[t] = atomicAdd(&gCur[t], hist[t]);
    __syncthreads();
    for (int i = t; i < CHUNK; i += 256) {
        int e = e0 + i;
        if (e >= E) continue;
        int c = col[e];
        int b = c >> BSH2;
        int pos = base[b] + atomicAdd(&cur[b], 1);
        if (pos < CAPB)   // statistically impossible overflow; guard anyway
            recA[(size_t)b * CAPB + pos] =
                make_uint2(((unsigned)(c & (BW2 - 1)) << 17) | (unsigned)row[e],
                           __float_as_uint(fabsf(ea[e])));
    }
}

// ---- pass B: per-bucket exact binning -> CSR (row,|ea|) + ptr/cnt + dis ----
__global__ __launch_bounds__(256) void passB_k(const int* __restrict__ gCur,
                                               const uint2* __restrict__ recA,
                                               uint2* __restrict__ rec,
                                               int* __restrict__ ptr,
                                               int* __restrict__ cnt,
                                               float* __restrict__ dis,
                                               int N, int CAPB) {
    __shared__ int hist[BW2], excl[BW2], cur[BW2];
    __shared__ float sumL[BW2];
    __shared__ int part[256];
    int b = blockIdx.x, t = threadIdx.x;
    int nrec = min(gCur[b], CAPB);
    for (int i = t; i < BW2; i += 256) { hist[i] = 0; cur[i] = 0; sumL[i] = 0.f; }
    __syncthreads();
    const uint2* ra = recA + (size_t)b * CAPB;
    for (int i = t; i < nrec; i += 256) {
        uint2 r = ra[i];
        int lc = r.x >> 17;
        atomicAdd(&hist[lc], 1);
        atomicAdd(&sumL[lc], __uint_as_float(r.y));
    }
    __syncthreads();
    // block exclusive scan over 512 counters (2 per thread)
    int s0 = hist[t * 2], s = s0 + hist[t * 2 + 1];
    part[t] = s;
    __syncthreads();
    for (int d = 1; d < 256; d <<= 1) {
        int v = (t >= d) ? part[t - d] : 0;
        __syncthreads();
        part[t] += v;
        __syncthreads();
    }
    int poff = t ? part[t - 1] : 0;
    excl[t * 2] = poff;
    excl[t * 2 + 1] = poff + s0;
    __syncthreads();
    for (int i = t; i < nrec; i += 256) {     // recA bucket is L2-hot (re-read)
        uint2 r = ra[i];
        int lc = r.x >> 17;
        int pos = atomicAdd(&cur[lc], 1);
        rec[(size_t)b * CAPB + excl[lc] + pos] = make_uint2(r.x & 0x1FFFFu, r.y);
    }
    int c0 = b << BSH2;
    for (int i = t; i < BW2; i += 256) {
        int node = c0 + i;
        if (node < N) {
            ptr[node] = b * CAPB + excl[i];
            cnt[node] = hist[i];
            dis[node] = rsqrtf(sumL[i] + 1.0f);
        }
    }
}

// Y[N,64] = X[N,K] @ W[K,64], output fp16. 256 thr = 16 rows x 64 cols.
template <int K>
__global__ __launch_bounds__(256) void gemm_k(const float* __restrict__ X,
                                              const float* __restrict__ W,
                                              __half* __restrict__ Y, int N) {
    __shared__ float xs[16 * K];
    const int tid = threadIdx.x;
    const int row0 = blockIdx.x * 16;
    const float4* X4 = reinterpret_cast<const float4*>(X + (size_t)row0 * K);
    float4* xs4 = reinterpret_cast<float4*>(xs);
    for (int idx = tid; idx < 16 * K / 4; idx += 256) {
        int r = row0 + (idx * 4) / K;
        xs4[idx] = (r < N) ? X4[idx] : float4{0.f, 0.f, 0.f, 0.f};
    }
    __syncthreads();
    const int c  = tid & 63;
    const int rg = tid >> 6;
    const float4* xp0 = reinterpret_cast<const float4*>(xs + (rg * 4 + 0) * K);
    const float4* xp1 = reinterpret_cast<const float4*>(xs + (rg * 4 + 1) * K);
    const float4* xp2 = reinterpret_cast<const float4*>(xs + (rg * 4 + 2) * K);
    const float4* xp3 = reinterpret_cast<const float4*>(xs + (rg * 4 + 3) * K);
    float a0 = 0.f, a1 = 0.f, a2 = 0.f, a3 = 0.f;
#pragma unroll 2
    for (int k4 = 0; k4 < K / 4; ++k4) {
        float4 x0 = xp0[k4], x1 = xp1[k4], x2 = xp2[k4], x3 = xp3[k4];
        const float* wp = W + k4 * 4 * 64 + c;
        float w0 = wp[0], w1 = wp[64], w2 = wp[128], w3 = wp[192];
        a0 = fmaf(x0.x, w0, a0); a0 = fmaf(x0.y, w1, a0);
        a0 = fmaf(x0.z, w2, a0); a0 = fmaf(x0.w, w3, a0);
        a1 = fmaf(x1.x, w0, a1); a1 = fmaf(x1.y, w1, a1);
        a1 = fmaf(x1.z, w2, a1); a1 = fmaf(x1.w, w3, a1);
        a2 = fmaf(x2.x, w0, a2); a2 = fmaf(x2.y, w1, a2);
        a2 = fmaf(x2.z, w2, a2); a2 = fmaf(x2.w, w3, a2);
        a3 = fmaf(x3.x, w0, a3); a3 = fmaf(x3.y, w1, a3);
        a3 = fmaf(x3.z, w2, a3); a3 = fmaf(x3.w, w3, a3);
    }
    int r = row0 + rg * 4;
    if (r < N)     Y[(size_t)r * 64 + c]       = __float2half(a0);
    if (r + 1 < N) Y[(size_t)(r + 1) * 64 + c] = __float2half(a1);
    if (r + 2 < N) Y[(size_t)(r + 2) * 64 + c] = __float2half(a2);
    if (r + 3 < N) Y[(size_t)(r + 3) * 64 + c] = __float2half(a3);
}

// CSR gather aggregation fused with self-loop + bias + ReLU.
// Wave per node, lane = feature. fp16 xw rows (128B/edge) gathered 8-wide
// unrolled -> 8 outstanding loads per wave (memory-level parallelism).
__global__ __launch_bounds__(256) void agg_fin_k(const int* __restrict__ ptr,
                                                 const int* __restrict__ cnt,
                                                 const uint2* __restrict__ rec,
                                                 const float* __restrict__ dis,
                                                 const __half* __restrict__ xw,
                                                 const float* __restrict__ bias,
                                                 float* __restrict__ h, int N) {
    int n = blockIdx.x * 4 + (threadIdx.x >> 6);
    if (n >= N) return;
    int lane = threadIdx.x & 63;
    int base = ptr[n], num = cnt[n];
    float acc = 0.f;
    for (int k0 = 0; k0 < num; k0 += 64) {
        int rem = min(num - k0, 64);
        int r = 0; float w = 0.f;
        if (lane < rem) {
            uint2 rv = rec[(size_t)base + k0 + lane];   // coalesced 512B
            r = (int)rv.x;
            w = __uint_as_float(rv.y) * dis[r];         // 400KB table: L2-hot
        }
        int k = 0;
        for (; k + 7 < rem; k += 8) {
            int   r0 = __shfl(r, k),     r1 = __shfl(r, k + 1);
            int   r2 = __shfl(r, k + 2), r3 = __shfl(r, k + 3);
            int   r4 = __shfl(r, k + 4), r5 = __shfl(r, k + 5);
            int   r6 = __shfl(r, k + 6), r7 = __shfl(r, k + 7);
            float w0 = __shfl(w, k),     w1 = __shfl(w, k + 1);
            float w2 = __shfl(w, k + 2), w3 = __shfl(w, k + 3);
            float w4 = __shfl(w, k + 4), w5 = __shfl(w, k + 5);
            float w6 = __shfl(w, k + 6), w7 = __shfl(w, k + 7);
            float v0 = __half2float(xw[(size_t)r0 * 64 + lane]);
            float v1 = __half2float(xw[(size_t)r1 * 64 + lane]);
            float v2 = __half2float(xw[(size_t)r2 * 64 + lane]);
            float v3 = __half2float(xw[(size_t)r3 * 64 + lane]);
            float v4 = __half2float(xw[(size_t)r4 * 64 + lane]);
            float v5 = __half2float(xw[(size_t)r5 * 64 + lane]);
            float v6 = __half2float(xw[(size_t)r6 * 64 + lane]);
            float v7 = __half2float(xw[(size_t)r7 * 64 + lane]);
            acc = fmaf(w0, v0, acc); acc = fmaf(w1, v1, acc);
            acc = fmaf(w2, v2, acc); acc = fmaf(w3, v3, acc);
            acc = fmaf(w4, v4, acc); acc = fmaf(w5, v5, acc);
            acc = fmaf(w6, v6, acc); acc = fmaf(w7, v7, acc);
        }
        for (; k < rem; ++k) {
            int rk = __shfl(r, k); float wk = __shfl(w, k);
            acc = fmaf(wk, __half2float(xw[(size_t)rk * 64 + lane]), acc);
        }
    }
    float d = dis[n];
    float sv = fmaf(d, __half2float(xw[(size_t)n * 64 + lane]), acc);
    h[(size_t)n * 64 + lane] = fmaxf(fmaf(d, sv, bias[lane]), 0.0f);
}

// Segmented heads: wave per contiguous node chunk; register pool accumulation,
// one coalesced atomic row per graph transition (batch is sorted).
__global__ __launch_bounds__(256) void heads_k(const float* __restrict__ h,
                                               const float* __restrict__ aw,
                                               const float* __restrict__ ab,
                                               const int* __restrict__ batch,
                                               float* __restrict__ logits,
                                               float* __restrict__ sums,
                                               float* __restrict__ counts,
                                               int N, int C) {
    int wave = blockIdx.x * 4 + (threadIdx.x >> 6);
    int lane = threadIdx.x & 63;
    int start = wave * C;
    if (start >= N) return;
    int end = min(start + C, N);
    float aww = aw[lane];
    float abv = ab[0];
    int cur = batch[start];
    float acc = 0.f;
    int cntv = 0;
    for (int i = start; i < end; ++i) {
        float hv = h[(size_t)i * 64 + lane];
        float p = hv * aww;
        for (int off = 32; off; off >>= 1) p += __shfl_down(p, off);
        if (lane == 0) logits[i] = p + abv;
        int g = batch[i];                      // wave-uniform
        if (g != cur) {
            atomicAdd(&sums[cur * 64 + lane], acc);
            if (lane == 0) atomicAdd(&counts[cur], (float)cntv);
            acc = 0.f; cntv = 0; cur = g;
        }
        acc += hv; ++cntv;
    }
    atomicAdd(&sums[cur * 64 + lane], acc);
    if (lane == 0) atomicAdd(&counts[cur], (float)cntv);
}

__global__ void value_k(const float* __restrict__ sums, const float* __restrict__ counts,
                        const float* __restrict__ cw, const float* __restrict__ cb,
                        float* __restrict__ val) {
    int g = blockIdx.x;
    int lane = threadIdx.x;  // block 64
    float cntv = fmaxf(counts[g], 1.0f);
    float p = (sums[g * 64 + lane] / cntv) * cw[lane];
    for (int off = 32; off; off >>= 1) p += __shfl_down(p, off);
    if (lane == 0) val[g] = p + cb[0];
}

extern "C" void kernel_launch(void* const* d_in, const int* in_sizes, int n_in,
                              void* d_out, int out_size, void* d_ws, size_t ws_size,
                              hipStream_t stream) {
    const float* x     = (const float*)d_in[0];
    const int*   ei    = (const int*)d_in[1];
    const float* ea    = (const float*)d_in[2];
    const int*   batch = (const int*)d_in[3];
    const float* W1    = (const float*)d_in[4];
    const float* b1    = (const float*)d_in[5];
    const float* W2    = (const float*)d_in[6];
    const float* b2    = (const float*)d_in[7];
    const float* aw    = (const float*)d_in[8];
    const float* ab    = (const float*)d_in[9];
    const float* cw    = (const float*)d_in[10];
    const float* cb    = (const float*)d_in[11];

    const int N = in_sizes[3];
    const int E = in_sizes[2];
    const int H = 64, G = 64;
    const int* row = ei;
    const int* col = ei + E;

    const int NB1  = (N + BW2 - 1) >> BSH2;                // coarse buckets (<=256)
    const int CAPB = (((E / NB1) * 5 / 4 + 256) + 1) & ~1; // ~1.25x mean, even

    // workspace layout (~72 MB)
    float*  dis    = (float*)d_ws;                          // N
    int*    gCur   = (int*)(dis + N);                       // NB1MAX
    uint2*  recA   = (uint2*)(gCur + NB1MAX);               // NB1*CAPB (8B rec)
    uint2*  rec    = recA + (size_t)NB1 * CAPB;             // NB1*CAPB
    int*    ptr    = (int*)(rec + (size_t)NB1 * CAPB);      // N
    int*    cnt    = ptr + N;                               // N
    __half* xwh    = (__half*)(cnt + N);                    // N*H fp16
    float*  bufB   = (float*)(xwh + (size_t)N * H);         // N*H f32 (h1/h2)
    float*  sums   = bufB + (size_t)N * H;                  // G*H
    float*  counts = sums + G * H;                          // G

    float* logits = (float*)d_out;              // N
    float* value  = logits + N;                 // G

    // ---- CSR build (shared by both layers; includes dis) ----
    hipMemsetAsync(gCur, 0, (size_t)NB1MAX * 4, stream);
    passA_k<<<(E + CHUNK - 1) / CHUNK, 256, 0, stream>>>(col, row, ea, gCur, recA, E, CAPB, NB1);
    passB_k<<<NB1, 256, 0, stream>>>(gCur, recA, rec, ptr, cnt, dis, N, CAPB);

    // ---- layer 1 ----
    gemm_k<128><<<(N + 15) / 16, 256, 0, stream>>>(x, W1, xwh, N);
    agg_fin_k<<<(N + 3) / 4, 256, 0, stream>>>(ptr, cnt, rec, dis, xwh, b1, bufB, N);

    // ---- layer 2 ----
    gemm_k<64><<<(N + 15) / 16, 256, 0, stream>>>(bufB, W2, xwh, N);
    agg_fin_k<<<(N + 3) / 4, 256, 0, stream>>>(ptr, cnt, rec, dis, xwh, b2, bufB, N);

    // ---- heads (segmented; batch sorted) ----
    hipMemsetAsync(sums, 0, (size_t)(G * H + G) * 4, stream);
    const int WAVES = 4096;
    const int C = (N + WAVES - 1) / WAVES;
    heads_k<<<WAVES / 4, 256, 0, stream>>>(bufB, aw, ab, batch, logits, sums, counts, N, C);
    value_k<<<G, 64, 0, stream>>>(sums, counts, cw, cb, value);
}

// Round 12
// 274.036 us; speedup vs baseline: 2.1273x; 1.0146x over previous
//
#include <hip/hip_runtime.h>
#include <hip/hip_fp16.h>

// GNNPolicy forward: 2-layer GCN + actor head + mean-pool critic head.
// N=100K, E=1.6M, H=64, G=64. CSR build: 2-level counting sort with
// block-private reservations; records carry (row,|ea|). xw stored fp16.
// agg_fin: 2 edges per wave-step, half2 lanes (dword loads), 16-edge unroll.

#define TB 256
#define BSH2 9
#define BW2 512          // nodes per coarse bucket
#define CHUNK 4096       // edges per passA block
#define NB1MAX 256       // max coarse buckets (N <= 131072, row fits 17 bits)

// ---- pass A: LDS histogram + region reservation + dense 8B-record append ----
// recA = ( (colLocal<<17) | row , |ea| )
__global__ __launch_bounds__(256) void passA_k(const int* __restrict__ col,
                                               const int* __restrict__ row,
                                               const float* __restrict__ ea,
                                               int* __restrict__ gCur,
                                               uint2* __restrict__ recA,
                                               int E, int CAPB, int NB1) {
    __shared__ int hist[NB1MAX], base[NB1MAX], cur[NB1MAX];
    int t = threadIdx.x;
    int e0 = blockIdx.x * CHUNK;
    if (t < NB1MAX) { hist[t] = 0; cur[t] = 0; }
    __syncthreads();
    for (int i = t; i < CHUNK; i += 256) {
        int e = e0 + i;
        if (e < E) atomicAdd(&hist[col[e] >> BSH2], 1);
    }
    __syncthreads();
    if (t < NB1) base[t] = atomicAdd(&gCur[t], hist[t]);
    __syncthreads();
    for (int i = t; i < CHUNK; i += 256) {
        int e = e0 + i;
        if (e >= E) continue;
        int c = col[e];
        int b = c >> BSH2;
        int pos = base[b] + atomicAdd(&cur[b], 1);
        if (pos < CAPB)   // statistically impossible overflow; guard anyway
            recA[(size_t)b * CAPB + pos] =
                make_uint2(((unsigned)(c & (BW2 - 1)) << 17) | (unsigned)row[e],
                           __float_as_uint(fabsf(ea[e])));
    }
}

// ---- pass B: per-bucket exact binning -> CSR (row,|ea|) + ptr/cnt + dis ----
__global__ __launch_bounds__(256) void passB_k(const int* __restrict__ gCur,
                                               const uint2* __restrict__ recA,
                                               uint2* __restrict__ rec,
                                               int* __restrict__ ptr,
                                               int* __restrict__ cnt,
                                               float* __restrict__ dis,
                                               int N, int CAPB) {
    __shared__ int hist[BW2], excl[BW2], cur[BW2];
    __shared__ float sumL[BW2];
    __shared__ int part[256];
    int b = blockIdx.x, t = threadIdx.x;
    int nrec = min(gCur[b], CAPB);
    for (int i = t; i < BW2; i += 256) { hist[i] = 0; cur[i] = 0; sumL[i] = 0.f; }
    __syncthreads();
    const uint2* ra = recA + (size_t)b * CAPB;
    for (int i = t; i < nrec; i += 256) {
        uint2 r = ra[i];
        int lc = r.x >> 17;
        atomicAdd(&hist[lc], 1);
        atomicAdd(&sumL[lc], __uint_as_float(r.y));
    }
    __syncthreads();
    // block exclusive scan over 512 counters (2 per thread)
    int s0 = hist[t * 2], s = s0 + hist[t * 2 + 1];
    part[t] = s;
    __syncthreads();
    for (int d = 1; d < 256; d <<= 1) {
        int v = (t >= d) ? part[t - d] : 0;
        __syncthreads();
        part[t] += v;
        __syncthreads();
    }
    int poff = t ? part[t - 1] : 0;
    excl[t * 2] = poff;
    excl[t * 2 + 1] = poff + s0;
    __syncthreads();
    for (int i = t; i < nrec; i += 256) {     // recA bucket is L2-hot (re-read)
        uint2 r = ra[i];
        int lc = r.x >> 17;
        int pos = atomicAdd(&cur[lc], 1);
        rec[(size_t)b * CAPB + excl[lc] + pos] = make_uint2(r.x & 0x1FFFFu, r.y);
    }
    int c0 = b << BSH2;
    for (int i = t; i < BW2; i += 256) {
        int node = c0 + i;
        if (node < N) {
            ptr[node] = b * CAPB + excl[i];
            cnt[node] = hist[i];
            dis[node] = rsqrtf(sumL[i] + 1.0f);
        }
    }
}

// Y[N,64] = X[N,K] @ W[K,64], output fp16. 256 thr = 16 rows x 64 cols.
template <int K>
__global__ __launch_bounds__(256) void gemm_k(const float* __restrict__ X,
                                              const float* __restrict__ W,
                                              __half* __restrict__ Y, int N) {
    __shared__ float xs[16 * K];
    const int tid = threadIdx.x;
    const int row0 = blockIdx.x * 16;
    const float4* X4 = reinterpret_cast<const float4*>(X + (size_t)row0 * K);
    float4* xs4 = reinterpret_cast<float4*>(xs);
    for (int idx = tid; idx < 16 * K / 4; idx += 256) {
        int r = row0 + (idx * 4) / K;
        xs4[idx] = (r < N) ? X4[idx] : float4{0.f, 0.f, 0.f, 0.f};
    }
    __syncthreads();
    const int c  = tid & 63;
    const int rg = tid >> 6;
    const float4* xp0 = reinterpret_cast<const float4*>(xs + (rg * 4 + 0) * K);
    const float4* xp1 = reinterpret_cast<const float4*>(xs + (rg * 4 + 1) * K);
    const float4* xp2 = reinterpret_cast<const float4*>(xs + (rg * 4 + 2) * K);
    const float4* xp3 = reinterpret_cast<const float4*>(xs + (rg * 4 + 3) * K);
    float a0 = 0.f, a1 = 0.f, a2 = 0.f, a3 = 0.f;
#pragma unroll 2
    for (int k4 = 0; k4 < K / 4; ++k4) {
        float4 x0 = xp0[k4], x1 = xp1[k4], x2 = xp2[k4], x3 = xp3[k4];
        const float* wp = W + k4 * 4 * 64 + c;
        float w0 = wp[0], w1 = wp[64], w2 = wp[128], w3 = wp[192];
        a0 = fmaf(x0.x, w0, a0); a0 = fmaf(x0.y, w1, a0);
        a0 = fmaf(x0.z, w2, a0); a0 = fmaf(x0.w, w3, a0);
        a1 = fmaf(x1.x, w0, a1); a1 = fmaf(x1.y, w1, a1);
        a1 = fmaf(x1.z, w2, a1); a1 = fmaf(x1.w, w3, a1);
        a2 = fmaf(x2.x, w0, a2); a2 = fmaf(x2.y, w1, a2);
        a2 = fmaf(x2.z, w2, a2); a2 = fmaf(x2.w, w3, a2);
        a3 = fmaf(x3.x, w0, a3); a3 = fmaf(x3.y, w1, a3);
        a3 = fmaf(x3.z, w2, a3); a3 = fmaf(x3.w, w3, a3);
    }
    int r = row0 + rg * 4;
    if (r < N)     Y[(size_t)r * 64 + c]       = __float2half(a0);
    if (r + 1 < N) Y[(size_t)(r + 1) * 64 + c] = __float2half(a1);
    if (r + 2 < N) Y[(size_t)(r + 2) * 64 + c] = __float2half(a2);
    if (r + 3 < N) Y[(size_t)(r + 3) * 64 + c] = __float2half(a3);
}

// CSR gather aggregation fused with self-loop + bias + ReLU.
// Wave per node. 2 edges per step: lanes 0-31 even edges, 32-63 odd edges;
// each lane loads one half2 (features 2fl,2fl+1) -> dword loads, half the
// instructions per edge. 16-edge unroll = 8 outstanding loads per lane.
// Partner halves combined via shfl(lane^32) at the end.
__global__ __launch_bounds__(256) void agg_fin_k(const int* __restrict__ ptr,
                                                 const int* __restrict__ cnt,
                                                 const uint2* __restrict__ rec,
                                                 const float* __restrict__ dis,
                                                 const __half2* __restrict__ xw2,
                                                 const float* __restrict__ bias,
                                                 float* __restrict__ h, int N) {
    int n = blockIdx.x * 4 + (threadIdx.x >> 6);
    if (n >= N) return;
    int lane = threadIdx.x & 63;
    int half_id = lane >> 5;          // 0: even edges, 1: odd edges
    int fl = lane & 31;               // feature pair (2fl, 2fl+1)
    int base = ptr[n], num = cnt[n];
    float ax = 0.f, ay = 0.f;
    for (int k0 = 0; k0 < num; k0 += 64) {
        int rem = min(num - k0, 64);
        int r = 0; float w = 0.f;
        if (lane < rem) {
            uint2 rv = rec[(size_t)base + k0 + lane];   // coalesced 512B
            r = (int)rv.x;
            w = __uint_as_float(rv.y) * dis[r];         // 400KB table: L2-hot
        }
        int k = 0;
        for (; k + 15 < rem; k += 16) {
            int i0 = k + half_id;
            int   ra0 = __shfl(r, i0),      ra1 = __shfl(r, i0 + 2);
            int   ra2 = __shfl(r, i0 + 4),  ra3 = __shfl(r, i0 + 6);
            int   ra4 = __shfl(r, i0 + 8),  ra5 = __shfl(r, i0 + 10);
            int   ra6 = __shfl(r, i0 + 12), ra7 = __shfl(r, i0 + 14);
            float wa0 = __shfl(w, i0),      wa1 = __shfl(w, i0 + 2);
            float wa2 = __shfl(w, i0 + 4),  wa3 = __shfl(w, i0 + 6);
            float wa4 = __shfl(w, i0 + 8),  wa5 = __shfl(w, i0 + 10);
            float wa6 = __shfl(w, i0 + 12), wa7 = __shfl(w, i0 + 14);
            __half2 v0 = xw2[(size_t)ra0 * 32 + fl];
            __half2 v1 = xw2[(size_t)ra1 * 32 + fl];
            __half2 v2 = xw2[(size_t)ra2 * 32 + fl];
            __half2 v3 = xw2[(size_t)ra3 * 32 + fl];
            __half2 v4 = xw2[(size_t)ra4 * 32 + fl];
            __half2 v5 = xw2[(size_t)ra5 * 32 + fl];
            __half2 v6 = xw2[(size_t)ra6 * 32 + fl];
            __half2 v7 = xw2[(size_t)ra7 * 32 + fl];
            float2 f;
            f = __half22float2(v0); ax = fmaf(wa0, f.x, ax); ay = fmaf(wa0, f.y, ay);
            f = __half22float2(v1); ax = fmaf(wa1, f.x, ax); ay = fmaf(wa1, f.y, ay);
            f = __half22float2(v2); ax = fmaf(wa2, f.x, ax); ay = fmaf(wa2, f.y, ay);
            f = __half22float2(v3); ax = fmaf(wa3, f.x, ax); ay = fmaf(wa3, f.y, ay);
            f = __half22float2(v4); ax = fmaf(wa4, f.x, ax); ay = fmaf(wa4, f.y, ay);
            f = __half22float2(v5); ax = fmaf(wa5, f.x, ax); ay = fmaf(wa5, f.y, ay);
            f = __half22float2(v6); ax = fmaf(wa6, f.x, ax); ay = fmaf(wa6, f.y, ay);
            f = __half22float2(v7); ax = fmaf(wa7, f.x, ax); ay = fmaf(wa7, f.y, ay);
        }
        for (; k + 1 < rem; k += 2) {
            int i = k + half_id;
            int ra = __shfl(r, i); float wa = __shfl(w, i);
            float2 f = __half22float2(xw2[(size_t)ra * 32 + fl]);
            ax = fmaf(wa, f.x, ax); ay = fmaf(wa, f.y, ay);
        }
        if (k < rem) {                 // single leftover edge: half 0 only
            int ra = __shfl(r, k); float wa = __shfl(w, k);
            if (half_id == 0) {
                float2 f = __half22float2(xw2[(size_t)ra * 32 + fl]);
                ax = fmaf(wa, f.x, ax); ay = fmaf(wa, f.y, ay);
            }
        }
    }
    // combine even/odd halves (partner lane has same fl)
    ax += __shfl(ax, lane ^ 32);
    ay += __shfl(ay, lane ^ 32);
    if (half_id == 0) {
        float d = dis[n];
        float2 xs = __half22float2(xw2[(size_t)n * 32 + fl]);
        float2 bb = reinterpret_cast<const float2*>(bias)[fl];
        float svx = fmaf(d, xs.x, ax);
        float svy = fmaf(d, xs.y, ay);
        float2 out;
        out.x = fmaxf(fmaf(d, svx, bb.x), 0.0f);
        out.y = fmaxf(fmaf(d, svy, bb.y), 0.0f);
        reinterpret_cast<float2*>(h)[(size_t)n * 32 + fl] = out;
    }
}

// Segmented heads: wave per contiguous node chunk; register pool accumulation,
// one coalesced atomic row per graph transition (batch is sorted).
__global__ __launch_bounds__(256) void heads_k(const float* __restrict__ h,
                                               const float* __restrict__ aw,
                                               const float* __restrict__ ab,
                                               const int* __restrict__ batch,
                                               float* __restrict__ logits,
                                               float* __restrict__ sums,
                                               float* __restrict__ counts,
                                               int N, int C) {
    int wave = blockIdx.x * 4 + (threadIdx.x >> 6);
    int lane = threadIdx.x & 63;
    int start = wave * C;
    if (start >= N) return;
    int end = min(start + C, N);
    float aww = aw[lane];
    float abv = ab[0];
    int cur = batch[start];
    float acc = 0.f;
    int cntv = 0;
    for (int i = start; i < end; ++i) {
        float hv = h[(size_t)i * 64 + lane];
        float p = hv * aww;
        for (int off = 32; off; off >>= 1) p += __shfl_down(p, off);
        if (lane == 0) logits[i] = p + abv;
        int g = batch[i];                      // wave-uniform
        if (g != cur) {
            atomicAdd(&sums[cur * 64 + lane], acc);
            if (lane == 0) atomicAdd(&counts[cur], (float)cntv);
            acc = 0.f; cntv = 0; cur = g;
        }
        acc += hv; ++cntv;
    }
    atomicAdd(&sums[cur * 64 + lane], acc);
    if (lane == 0) atomicAdd(&counts[cur], (float)cntv);
}

__global__ void value_k(const float* __restrict__ sums, const float* __restrict__ counts,
                        const float* __restrict__ cw, const float* __restrict__ cb,
                        float* __restrict__ val) {
    int g = blockIdx.x;
    int lane = threadIdx.x;  // block 64
    float cntv = fmaxf(counts[g], 1.0f);
    float p = (sums[g * 64 + lane] / cntv) * cw[lane];
    for (int off = 32; off; off >>= 1) p += __shfl_down(p, off);
    if (lane == 0) val[g] = p + cb[0];
}

extern "C" void kernel_launch(void* const* d_in, const int* in_sizes, int n_in,
                              void* d_out, int out_size, void* d_ws, size_t ws_size,
                              hipStream_t stream) {
    const float* x     = (const float*)d_in[0];
    const int*   ei    = (const int*)d_in[1];
    const float* ea    = (const float*)d_in[2];
    const int*   batch = (const int*)d_in[3];
    const float* W1    = (const float*)d_in[4];
    const float* b1    = (const float*)d_in[5];
    const float* W2    = (const float*)d_in[6];
    const float* b2    = (const float*)d_in[7];
    const float* aw    = (const float*)d_in[8];
    const float* ab    = (const float*)d_in[9];
    const float* cw    = (const float*)d_in[10];
    const float* cb    = (const float*)d_in[11];

    const int N = in_sizes[3];
    const int E = in_sizes[2];
    const int H = 64, G = 64;
    const int* row = ei;
    const int* col = ei + E;

    const int NB1  = (N + BW2 - 1) >> BSH2;                // coarse buckets (<=256)
    const int CAPB = (((E / NB1) * 5 / 4 + 256) + 1) & ~1; // ~1.25x mean, even

    // workspace layout (~72 MB)
    float*  dis    = (float*)d_ws;                          // N
    int*    gCur   = (int*)(dis + N);                       // NB1MAX
    uint2*  recA   = (uint2*)(gCur + NB1MAX);               // NB1*CAPB (8B rec)
    uint2*  rec    = recA + (size_t)NB1 * CAPB;             // NB1*CAPB
    int*    ptr    = (int*)(rec + (size_t)NB1 * CAPB);      // N
    int*    cnt    = ptr + N;                               // N
    __half* xwh    = (__half*)(cnt + N);                    // N*H fp16
    float*  bufB   = (float*)(xwh + (size_t)N * H);         // N*H f32 (h1/h2)
    float*  sums   = bufB + (size_t)N * H;                  // G*H
    float*  counts = sums + G * H;                          // G

    float* logits = (float*)d_out;              // N
    float* value  = logits + N;                 // G

    // ---- CSR build (shared by both layers; includes dis) ----
    hipMemsetAsync(gCur, 0, (size_t)NB1MAX * 4, stream);
    passA_k<<<(E + CHUNK - 1) / CHUNK, 256, 0, stream>>>(col, row, ea, gCur, recA, E, CAPB, NB1);
    passB_k<<<NB1, 256, 0, stream>>>(gCur, recA, rec, ptr, cnt, dis, N, CAPB);

    // ---- layer 1 ----
    gemm_k<128><<<(N + 15) / 16, 256, 0, stream>>>(x, W1, xwh, N);
    agg_fin_k<<<(N + 3) / 4, 256, 0, stream>>>(ptr, cnt, rec, dis,
                                               (const __half2*)xwh, b1, bufB, N);

    // ---- layer 2 ----
    gemm_k<64><<<(N + 15) / 16, 256, 0, stream>>>(bufB, W2, xwh, N);
    agg_fin_k<<<(N + 3) / 4, 256, 0, stream>>>(ptr, cnt, rec, dis,
                                               (const __half2*)xwh, b2, bufB, N);

    // ---- heads (segmented; batch sorted) ----
    hipMemsetAsync(sums, 0, (size_t)(G * H + G) * 4, stream);
    const int WAVES = 4096;
    const int C = (N + WAVES - 1) / WAVES;
    heads_k<<<WAVES / 4, 256, 0, stream>>>(bufB, aw, ab, batch, logits, sums, counts, N, C);
    value_k<<<G, 64, 0, stream>>>(sums, counts, cw, cb, value);
}